// Round 7
// baseline (488.485 us; speedup 1.0000x reference)
//
#include <hip/hip_runtime.h>

#define KCL 41
#define BB 8
#define CC 128
#define HWSZ 25600
#define PP 200          // chunks per (b) plane = HW/C
#define ASTR 132        // A c-stride (128 + 4 pad), float4-aligned

// ---------------- init: zero accumulators in workspace ----------------
__global__ __launch_bounds__(256) void init_ws(float* ws) {
    for (int i = threadIdx.x; i < KCL * KCL + 3 * KCL; i += 256) ws[i] = 0.f;
}

// ---------------- main: per-(b,p) atomic scatter + Gram partials ----------------
__global__ __launch_bounds__(256) void main_k(const float* __restrict__ fs,
                                              const float* __restrict__ ft,
                                              const int* __restrict__ labels,
                                              float* __restrict__ G,
                                              float* __restrict__ NS,
                                              float* __restrict__ NT,
                                              int* __restrict__ CNT)
{
    __shared__ int lab[128];
    __shared__ unsigned lab4b[32];                    // 4 packed label bytes per word
    __shared__ unsigned long long mask64[2][KCL];     // for CNT only
    __shared__ __align__(16) float A[2][KCL][ASTR];   // 43.3 KB class x channel sums

    const int bp = blockIdx.x;
    const int b = bp / PP, p = bp % PP;
    const int tid = threadIdx.x;

    // zero A (absent classes must stay 0; ds_add needs zeroed base)
    {
        float* a0 = &A[0][0][0];
        for (int i = tid; i < 2 * KCL * ASTR; i += 256) a0[i] = 0.f;
    }
    if (tid < 128) lab[tid] = labels[b * HWSZ + p * 128 + tid];
    __syncthreads();

    // pack labels 4-per-word (each scatter thread needs exactly one word)
    if (tid < 32)
        lab4b[tid] = (unsigned)lab[4 * tid] | ((unsigned)lab[4 * tid + 1] << 8)
                   | ((unsigned)lab[4 * tid + 2] << 16) | ((unsigned)lab[4 * tid + 3] << 24);

    // per-class ballot masks (wave-uniform) -> pixel counts
    const int wv = tid >> 6, ln = tid & 63;
    if (wv < 2) {
        int myl = lab[(wv << 6) + ln];
        for (int cl = 0; cl < KCL; ++cl) {
            unsigned long long mm = __ballot(myl == cl);
            if (ln == 0) mask64[wv][cl] = mm;
        }
    }
    __syncthreads();
    if (tid < KCL)
        atomicAdd(&CNT[tid], (int)(__popcll(mask64[0][tid]) + __popcll(mask64[1][tid])));

    // ---- scatter: global float4 read -> 4 LDS atomic adds (fire-and-forget) ----
    // thread covers pixels j = 4*(tid&31)+{0..3} for channels c = 8k + (tid>>5)
    const unsigned labs = lab4b[tid & 31];
    const int cl0 = labs & 255, cl1 = (labs >> 8) & 255,
              cl2 = (labs >> 16) & 255, cl3 = (labs >> 24) & 255;
    const int c0 = tid >> 5;   // 0..7
    const size_t base_g = (size_t)b * CC * HWSZ + (size_t)p * 128 + (size_t)((tid & 31) << 2);

    #pragma unroll
    for (int k = 0; k < 16; ++k) {
        const int c = (k << 3) + c0;
        float4 v = *(const float4*)(fs + base_g + (size_t)c * HWSZ);
        atomicAdd(&A[0][cl0][c], v.x);
        atomicAdd(&A[0][cl1][c], v.y);
        atomicAdd(&A[0][cl2][c], v.z);
        atomicAdd(&A[0][cl3][c], v.w);
    }
    #pragma unroll
    for (int k = 0; k < 16; ++k) {
        const int c = (k << 3) + c0;
        float4 v = *(const float4*)(ft + base_g + (size_t)c * HWSZ);
        atomicAdd(&A[1][cl0][c], v.x);
        atomicAdd(&A[1][cl1][c], v.y);
        atomicAdd(&A[1][cl2][c], v.z);
        atomicAdd(&A[1][cl3][c], v.w);
    }
    __syncthreads();

    // Gram: G[i][j] += sum_c A[0][i][c]*A[1][j][c]; 16x16 threads x 3x3 tile (48x48 >= 41x41)
    {
        const int ti = tid >> 4, tj = tid & 15;
        float acc[3][3] = {};
        for (int c4 = 0; c4 < 32; ++c4) {
            float4 av[3], bv[3];
            #pragma unroll
            for (int u = 0; u < 3; ++u) {
                int I = ti + (u << 4); if (I > KCL - 1) I = KCL - 1;  // clamped dup, discarded at write
                int J = tj + (u << 4); if (J > KCL - 1) J = KCL - 1;
                av[u] = *(const float4*)(&A[0][I][c4 << 2]);
                bv[u] = *(const float4*)(&A[1][J][c4 << 2]);
            }
            #pragma unroll
            for (int u = 0; u < 3; ++u)
                #pragma unroll
                for (int v = 0; v < 3; ++v)
                    acc[u][v] += av[u].x * bv[v].x + av[u].y * bv[v].y
                               + av[u].z * bv[v].z + av[u].w * bv[v].w;
        }
        #pragma unroll
        for (int u = 0; u < 3; ++u) {
            int I = ti + (u << 4); if (I >= KCL) continue;
            #pragma unroll
            for (int v = 0; v < 3; ++v) {
                int J = tj + (v << 4); if (J >= KCL) continue;
                atomicAdd(&G[I * KCL + J], acc[u][v]);
            }
        }
    }

    // squared-norm partials
    if (tid < KCL) {
        float ss = 0.f, tt = 0.f;
        for (int c4 = 0; c4 < 32; ++c4) {
            float4 a  = *(const float4*)(&A[0][tid][c4 << 2]);
            float4 b2 = *(const float4*)(&A[1][tid][c4 << 2]);
            ss += a.x * a.x + a.y * a.y + a.z * a.z + a.w * a.w;
            tt += b2.x * b2.x + b2.y * b2.y + b2.z * b2.z + b2.w * b2.w;
        }
        atomicAdd(&NS[tid], ss);
        atomicAdd(&NT[tid], tt);
    }
}

// ---------------- finalize: cosine logits, logsumexp, loss ----------------
__global__ void finalize(const float* __restrict__ G,
                         const float* __restrict__ NS,
                         const float* __restrict__ NT,
                         const int* __restrict__ CNT,
                         float* __restrict__ out)
{
    __shared__ float sn[KCL], tnn[KCL];
    const int t = threadIdx.x;  // 64 threads = 1 wave
    if (t < KCL) {
        sn[t]  = fmaxf(sqrtf(NS[t]), 1e-12f);
        tnn[t] = fmaxf(sqrtf(NT[t]), 1e-12f);
    }
    __syncthreads();
    float term = 0.f; int pres = 0;
    if (t < KCL) {
        const float inv = 10.f / sn[t];   // 1/TEMP = 10
        float l[KCL];
        float mx = -1e30f, diag = 0.f;
        #pragma unroll
        for (int j = 0; j < KCL; ++j) {
            l[j] = G[t * KCL + j] * inv / tnn[j];
            if (l[j] > mx) mx = l[j];
            if (j == t) diag = l[j];
        }
        float s = 0.f;
        #pragma unroll
        for (int j = 0; j < KCL; ++j) s += expf(l[j] - mx);
        float lse = logf(s) + mx;
        pres = (CNT[t] > 0) ? 1 : 0;
        term = pres ? (lse - diag) : 0.f;
    }
    #pragma unroll
    for (int off = 32; off > 0; off >>= 1) {
        term += __shfl_down(term, off);
        pres += __shfl_down(pres, off);
    }
    if (t == 0) out[0] = term / (float)pres;
}

extern "C" void kernel_launch(void* const* d_in, const int* in_sizes, int n_in,
                              void* d_out, int out_size, void* d_ws, size_t ws_size,
                              hipStream_t stream) {
    const float* fs     = (const float*)d_in[0];
    const float* ft     = (const float*)d_in[1];
    const int*   labels = (const int*)d_in[2];
    float* G  = (float*)d_ws;
    float* NS = G + KCL * KCL;
    float* NT = NS + KCL;
    int*   CNT = (int*)(NT + KCL);
    float* out = (float*)d_out;

    hipLaunchKernelGGL(init_ws, dim3(1), dim3(256), 0, stream, G);
    hipLaunchKernelGGL(main_k, dim3(BB * PP), dim3(256), 0, stream,
                       fs, ft, labels, G, NS, NT, CNT);
    hipLaunchKernelGGL(finalize, dim3(1), dim3(64), 0, stream, G, NS, NT, CNT, out);
}

// Round 8
// 470.004 us; speedup vs baseline: 1.0393x; 1.0393x over previous
//
#include <hip/hip_runtime.h>

#define KCL 41
#define BB 8
#define CC 128
#define HWSZ 25600
#define PP 200          // chunks per (b) plane = HW/C
#define ASTR 132        // A class-row stride in floats (128 + 4 pad)

// ---------------- init: zero accumulators in workspace ----------------
__global__ __launch_bounds__(256) void init_ws(float* ws) {
    for (int i = threadIdx.x; i < KCL * KCL + 3 * KCL; i += 256) ws[i] = 0.f;
}

// ---------------- main: per-(b,p) column-exclusive atomic scatter + Gram ----------------
__global__ __launch_bounds__(256) void main_k(const float* __restrict__ fs,
                                              const float* __restrict__ ft,
                                              const int* __restrict__ labels,
                                              float* __restrict__ G,
                                              float* __restrict__ NS,
                                              float* __restrict__ NT,
                                              int* __restrict__ CNT)
{
    __shared__ int lab[128];
    __shared__ unsigned lab4b[32];                    // 4 packed label bytes per word
    __shared__ unsigned long long mask64[2][KCL];     // for CNT only
    __shared__ __align__(16) float A[2][KCL][ASTR];   // 43.3 KB class x channel sums

    const int bp = blockIdx.x;
    const int b = bp / PP, p = bp % PP;
    const int tid = threadIdx.x;

    // zero A vectorized (2*41*132 = 10824 floats = 2706 float4)
    {
        float4* a4 = (float4*)&A[0][0][0];
        const float4 z = make_float4(0.f, 0.f, 0.f, 0.f);
        for (int i = tid; i < 2706; i += 256) a4[i] = z;
    }
    if (tid < 128) lab[tid] = labels[b * HWSZ + p * 128 + tid];
    __syncthreads();

    // pack labels 4-per-word (scatter reads these wave-uniformly)
    if (tid < 32)
        lab4b[tid] = (unsigned)lab[4 * tid] | ((unsigned)lab[4 * tid + 1] << 8)
                   | ((unsigned)lab[4 * tid + 2] << 16) | ((unsigned)lab[4 * tid + 3] << 24);

    // per-class ballot masks (wave-uniform) -> pixel counts
    const int wv = tid >> 6, ln = tid & 63;
    if (wv < 2) {
        int myl = lab[(wv << 6) + ln];
        for (int cl = 0; cl < KCL; ++cl) {
            unsigned long long mm = __ballot(myl == cl);
            if (ln == 0) mask64[wv][cl] = mm;
        }
    }
    __syncthreads();
    if (tid < KCL)
        atomicAdd(&CNT[tid], (int)(__popcll(mask64[0][tid]) + __popcll(mask64[1][tid])));

    // ---- scatter: thread owns column (tn, c) exclusively; sweeps 128 pixels ----
    // Per ds_add instr: cl is wave-uniform, c lane-distinct -> conflict-free, R=1.
    {
        const int tn = tid >> 7;           // 0: fs, 1: ft
        const int c  = tid & 127;
        const float* __restrict__ f = tn ? ft : fs;
        const float* __restrict__ row = f + (size_t)b * CC * HWSZ + (size_t)c * HWSZ + (size_t)p * 128;
        float* __restrict__ Acol = &A[tn][0][c];   // + cl*ASTR per class

        #pragma unroll
        for (int bt = 0; bt < 4; ++bt) {
            float4 w[8];
            #pragma unroll
            for (int k = 0; k < 8; ++k)
                w[k] = *(const float4*)(row + (bt << 5) + (k << 2));
            #pragma unroll
            for (int k = 0; k < 8; ++k) {
                const unsigned word = lab4b[(bt << 3) + k];   // wave-uniform broadcast
                atomicAdd(&Acol[(word & 255u) * ASTR],         w[k].x);
                atomicAdd(&Acol[((word >> 8) & 255u) * ASTR],  w[k].y);
                atomicAdd(&Acol[((word >> 16) & 255u) * ASTR], w[k].z);
                atomicAdd(&Acol[(word >> 24) * ASTR],          w[k].w);
            }
        }
    }
    __syncthreads();

    // Gram: G[i][j] += sum_c A[0][i][c]*A[1][j][c]; 16x16 threads x 3x3 tile (48x48 >= 41x41)
    {
        const int ti = tid >> 4, tj = tid & 15;
        float acc[3][3] = {};
        for (int c4 = 0; c4 < 32; ++c4) {
            float4 av[3], bv[3];
            #pragma unroll
            for (int u = 0; u < 3; ++u) {
                int I = ti + (u << 4); if (I > KCL - 1) I = KCL - 1;  // clamped dup, discarded at write
                int J = tj + (u << 4); if (J > KCL - 1) J = KCL - 1;
                av[u] = *(const float4*)(&A[0][I][c4 << 2]);
                bv[u] = *(const float4*)(&A[1][J][c4 << 2]);
            }
            #pragma unroll
            for (int u = 0; u < 3; ++u)
                #pragma unroll
                for (int v = 0; v < 3; ++v)
                    acc[u][v] += av[u].x * bv[v].x + av[u].y * bv[v].y
                               + av[u].z * bv[v].z + av[u].w * bv[v].w;
        }
        #pragma unroll
        for (int u = 0; u < 3; ++u) {
            int I = ti + (u << 4); if (I >= KCL) continue;
            #pragma unroll
            for (int v = 0; v < 3; ++v) {
                int J = tj + (v << 4); if (J >= KCL) continue;
                atomicAdd(&G[I * KCL + J], acc[u][v]);
            }
        }
    }

    // squared-norm partials
    if (tid < KCL) {
        float ss = 0.f, tt = 0.f;
        for (int c4 = 0; c4 < 32; ++c4) {
            float4 a  = *(const float4*)(&A[0][tid][c4 << 2]);
            float4 b2 = *(const float4*)(&A[1][tid][c4 << 2]);
            ss += a.x * a.x + a.y * a.y + a.z * a.z + a.w * a.w;
            tt += b2.x * b2.x + b2.y * b2.y + b2.z * b2.z + b2.w * b2.w;
        }
        atomicAdd(&NS[tid], ss);
        atomicAdd(&NT[tid], tt);
    }
}

// ---------------- finalize: cosine logits, logsumexp, loss ----------------
__global__ void finalize(const float* __restrict__ G,
                         const float* __restrict__ NS,
                         const float* __restrict__ NT,
                         const int* __restrict__ CNT,
                         float* __restrict__ out)
{
    __shared__ float sn[KCL], tnn[KCL];
    const int t = threadIdx.x;  // 64 threads = 1 wave
    if (t < KCL) {
        sn[t]  = fmaxf(sqrtf(NS[t]), 1e-12f);
        tnn[t] = fmaxf(sqrtf(NT[t]), 1e-12f);
    }
    __syncthreads();
    float term = 0.f; int pres = 0;
    if (t < KCL) {
        const float inv = 10.f / sn[t];   // 1/TEMP = 10
        float l[KCL];
        float mx = -1e30f, diag = 0.f;
        #pragma unroll
        for (int j = 0; j < KCL; ++j) {
            l[j] = G[t * KCL + j] * inv / tnn[j];
            if (l[j] > mx) mx = l[j];
            if (j == t) diag = l[j];
        }
        float s = 0.f;
        #pragma unroll
        for (int j = 0; j < KCL; ++j) s += expf(l[j] - mx);
        float lse = logf(s) + mx;
        pres = (CNT[t] > 0) ? 1 : 0;
        term = pres ? (lse - diag) : 0.f;
    }
    #pragma unroll
    for (int off = 32; off > 0; off >>= 1) {
        term += __shfl_down(term, off);
        pres += __shfl_down(pres, off);
    }
    if (t == 0) out[0] = term / (float)pres;
}

extern "C" void kernel_launch(void* const* d_in, const int* in_sizes, int n_in,
                              void* d_out, int out_size, void* d_ws, size_t ws_size,
                              hipStream_t stream) {
    const float* fs     = (const float*)d_in[0];
    const float* ft     = (const float*)d_in[1];
    const int*   labels = (const int*)d_in[2];
    float* G  = (float*)d_ws;
    float* NS = G + KCL * KCL;
    float* NT = NS + KCL;
    int*   CNT = (int*)(NT + KCL);
    float* out = (float*)d_out;

    hipLaunchKernelGGL(init_ws, dim3(1), dim3(256), 0, stream, G);
    hipLaunchKernelGGL(main_k, dim3(BB * PP), dim3(256), 0, stream,
                       fs, ft, labels, G, NS, NT, CNT);
    hipLaunchKernelGGL(finalize, dim3(1), dim3(64), 0, stream, G, NS, NT, CNT, out);
}